// Round 3
// baseline (490.053 us; speedup 1.0000x reference)
//
#include <hip/hip_runtime.h>
#include <math.h>

#define NROWS 65536
#define NC    1000
#define NTH   21
// ws layout (floats): [0,N) unc | [N,2N) conf_signed
// | 2N: 88 bins | 2N+1024: ce_sum | 2N+2048: umin_bits | 2N+3072: umax_bits
// (scalars padded 4KB apart to land on different memory channels for atomics)

__device__ __forceinline__ void upd_max(float v, int i, float& m, int& mi) {
    if (v > m) { m = v; mi = i; }
}

__global__ void k0_init(float* bins, float* ce_sum, unsigned* umin_b, unsigned* umax_b) {
    int i = threadIdx.x;
    if (i < 88) bins[i] = 0.f;
    if (i == 88) *ce_sum = 0.f;
    if (i == 89) *umin_b = 0x7f800000u;  // +inf
    if (i == 90) *umax_b = 0u;
}

__global__ __launch_bounds__(256) void k1_rowstats(
        const float* __restrict__ logits, const int* __restrict__ labels,
        float* __restrict__ unc_o, float* __restrict__ confs_o,
        float* ce_sum, unsigned* umin_b, unsigned* umax_b)
{
    const int wave = threadIdx.x >> 6;
    const int lane = threadIdx.x & 63;
    const int row  = (blockIdx.x << 2) + wave;
    const float4* rp = (const float4*)(logits + (size_t)row * NC);

    // 250 float4 per row; lane handles f4 indices lane, lane+64, lane+128, lane+192
    float4 r0 = rp[lane];
    float4 r1 = rp[lane + 64];
    float4 r2 = rp[lane + 128];
    float4 r3 = make_float4(-1e30f, -1e30f, -1e30f, -1e30f);
    if (lane < 250 - 192) r3 = rp[lane + 192];

    // local max + argmax (increasing index order => first-occurrence tie-break)
    float m = -1e30f; int mi = 0;
    int b0 = lane << 2;
    upd_max(r0.x, b0 + 0, m, mi); upd_max(r0.y, b0 + 1, m, mi);
    upd_max(r0.z, b0 + 2, m, mi); upd_max(r0.w, b0 + 3, m, mi);
    int b1 = (lane + 64) << 2;
    upd_max(r1.x, b1 + 0, m, mi); upd_max(r1.y, b1 + 1, m, mi);
    upd_max(r1.z, b1 + 2, m, mi); upd_max(r1.w, b1 + 3, m, mi);
    int b2 = (lane + 128) << 2;
    upd_max(r2.x, b2 + 0, m, mi); upd_max(r2.y, b2 + 1, m, mi);
    upd_max(r2.z, b2 + 2, m, mi); upd_max(r2.w, b2 + 3, m, mi);
    int b3 = (lane + 192) << 2;
    upd_max(r3.x, b3 + 0, m, mi); upd_max(r3.y, b3 + 1, m, mi);
    upd_max(r3.z, b3 + 2, m, mi); upd_max(r3.w, b3 + 3, m, mi);

    // wave butterfly argmax (prefer smaller index on ties)
    #pragma unroll
    for (int off = 1; off < 64; off <<= 1) {
        float om = __shfl_xor(m, off, 64);
        int   oi = __shfl_xor(mi, off, 64);
        if (om > m || (om == m && oi < mi)) { m = om; mi = oi; }
    }

    // exp sums; sentinel -1e30 underflows exp to 0, 0*(-1e30) = -0 (no NaN)
    float se = 0.f, sx = 0.f;
#define ACCUM(v) { float t_ = (v) - m; float e_ = __expf(t_); se += e_; sx = fmaf(e_, t_, sx); }
    ACCUM(r0.x) ACCUM(r0.y) ACCUM(r0.z) ACCUM(r0.w)
    ACCUM(r1.x) ACCUM(r1.y) ACCUM(r1.z) ACCUM(r1.w)
    ACCUM(r2.x) ACCUM(r2.y) ACCUM(r2.z) ACCUM(r2.w)
    ACCUM(r3.x) ACCUM(r3.y) ACCUM(r3.z) ACCUM(r3.w)
#undef ACCUM
    #pragma unroll
    for (int off = 1; off < 64; off <<= 1) {
        se += __shfl_xor(se, off, 64);
        sx += __shfl_xor(sx, off, 64);
    }

    float Z    = se;
    float logZ = logf(Z);
    float conf = 1.0f / Z;            // max prob = exp(m-m)/Z
    float uncv = logZ - sx / Z;       // entropy

    int label = labels[row];          // wave-uniform scalar load
    int f4 = label >> 2, slot = label & 3, it = f4 >> 6;
    float4 q = (it == 0) ? r0 : (it == 1) ? r1 : (it == 2) ? r2 : r3;
    float cand = (slot == 0) ? q.x : (slot == 1) ? q.y : (slot == 2) ? q.z : q.w;
    float xl = __shfl(cand, f4 & 63, 64);

    __shared__ float s_u[4], s_lp[4];
    if (lane == 0) {
        unc_o[row]   = uncv;
        confs_o[row] = (mi == label) ? conf : -conf;  // sign carries accuracy bit
        s_u[wave]  = uncv;
        s_lp[wave] = (xl - m) - logZ;
    }
    __syncthreads();
    // block-level reduce over the 4 rows, then 3 fire-and-forget atomics
    if (threadIdx.x == 0) {
        float mn = fminf(fminf(s_u[0], s_u[1]), fminf(s_u[2], s_u[3]));
        float mx = fmaxf(fmaxf(s_u[0], s_u[1]), fmaxf(s_u[2], s_u[3]));
        float s  = (s_lp[0] + s_lp[1]) + (s_lp[2] + s_lp[3]);
        atomicAdd(ce_sum, s);
        atomicMin(umin_b, __float_as_uint(mn));  // entropy > 0: uint order == float order
        atomicMax(umax_b, __float_as_uint(mx));
    }
}

__global__ __launch_bounds__(256) void k3_hist(
        const float* __restrict__ unc, const float* __restrict__ confs,
        const unsigned* __restrict__ umin_b, const unsigned* __restrict__ umax_b,
        float* __restrict__ bins)
{
    __shared__ float h[88];
    for (int i = threadIdx.x; i < 88; i += 256) h[i] = 0.f;
    __syncthreads();
    float umin = __uint_as_float(*umin_b);
    float umax = __uint_as_float(*umax_b);
    float du = umax - umin;

    int i = blockIdx.x * 256 + threadIdx.x;
    float u  = unc[i];
    float cs = confs[i];
    float conf = fabsf(cs);
    bool  acc  = cs > 0.f;
    float tu = tanhf(u);

    // bucket = smallest t with u <= umin + (t*0.05)*du ; 21 => never certain
    int b = NTH;
    #pragma unroll
    for (int t = NTH - 1; t >= 0; --t) {
        float th = umin + ((float)t * 0.05f) * du;
        if (u <= th) b = t;
    }
    float w = acc ? conf : (1.f - conf);
    int base = acc ? 0 : 44;
    atomicAdd(&h[base + b],       w * (1.f - tu));  // -> n_ac / n_ic (certain side)
    atomicAdd(&h[base + 22 + b],  w * tu);          // -> n_au / n_iu (uncertain side)
    __syncthreads();
    for (int i2 = threadIdx.x; i2 < 88; i2 += 256) {
        float v = h[i2];
        if (v != 0.f) atomicAdd(&bins[i2], v);
    }
}

__global__ void k4_final(const float* __restrict__ bins, const float* __restrict__ ce_sum,
                         float* __restrict__ out)
{
    if (threadIdx.x != 0 || blockIdx.x != 0) return;
    float tot_au = 0.f, tot_iu = 0.f;
    for (int b = 0; b < 22; ++b) { tot_au += bins[22 + b]; tot_iu += bins[66 + b]; }
    float cac = 0.f, cau = 0.f, cic = 0.f, ciu = 0.f;
    float avu[NTH];
    for (int t = 0; t < NTH; ++t) {
        cac += bins[t]; cau += bins[22 + t]; cic += bins[44 + t]; ciu += bins[66 + t];
        float nac = cac, nau = tot_au - cau, nic = cic, niu = tot_iu - ciu;
        avu[t] = (nac + niu) / (nac + nau + nic + niu + 1e-12f);
    }
    float auc = 0.f;
    for (int t = 0; t + 1 < NTH; ++t) auc += 0.5f * (avu[t + 1] + avu[t]) * 0.05f;
    float avu_loss = -3.0f * logf(auc + 1e-12f);
    float ce = -(*ce_sum) / (float)NROWS;
    out[0] = avu_loss + ce;
}

extern "C" void kernel_launch(void* const* d_in, const int* in_sizes, int n_in,
                              void* d_out, int out_size, void* d_ws, size_t ws_size,
                              hipStream_t stream)
{
    const float* logits = (const float*)d_in[0];
    const int*   labels = (const int*)d_in[1];
    float* ws    = (float*)d_ws;
    float* unc   = ws;
    float* confs = ws + NROWS;
    float* bins  = ws + 2 * NROWS;                // 88 floats
    float* ce_sum = ws + 2 * NROWS + 1024;        // padded 4KB apart
    unsigned* umin_b = (unsigned*)(ws + 2 * NROWS + 2048);
    unsigned* umax_b = (unsigned*)(ws + 2 * NROWS + 3072);

    hipLaunchKernelGGL(k0_init, dim3(1), dim3(128), 0, stream, bins, ce_sum, umin_b, umax_b);
    hipLaunchKernelGGL(k1_rowstats, dim3(NROWS / 4), dim3(256), 0, stream,
                       logits, labels, unc, confs, ce_sum, umin_b, umax_b);
    hipLaunchKernelGGL(k3_hist, dim3(NROWS / 256), dim3(256), 0, stream,
                       unc, confs, umin_b, umax_b, bins);
    hipLaunchKernelGGL(k4_final, dim3(1), dim3(64), 0, stream,
                       bins, ce_sum, (float*)d_out);
}

// Round 4
// 371.943 us; speedup vs baseline: 1.3175x; 1.3175x over previous
//
#include <hip/hip_runtime.h>
#include <math.h>

#define NROWS 65536
#define NC    1000
#define NTH   21
#define NBLK1 4096   // k1: 4 waves/block x 4 rows/wave = 16 rows/block
// ws layout (floats): [0,N) unc | [N,2N) conf_signed
// | 2N: 88 bins | 2N+1024: ce_sum | 2N+2048: umin_bits | 2N+3072: umax_bits
// | 2N+4096: blk_mn[4096] | +4096: blk_mx[4096] | +4096: blk_s[4096]

// left-priority pairwise max: keeps smaller original index on ties (== sequential
// first-occurrence semantics when pairing respects increasing index order)
__device__ __forceinline__ void amax2(float va, int ia, float vb, int ib,
                                      float& vo, int& io) {
    bool t = (va >= vb);
    vo = t ? va : vb;
    io = t ? ia : ib;
}

__device__ __forceinline__ void row_process(
        float4 r0, float4 r1, float4 r2, float4 r3,
        int lane, int label, int row,
        float* __restrict__ unc_o, float* __restrict__ confs_o,
        float& mn, float& mx, float& ssum)
{
    // ---- tournament argmax over this lane's 16 values (depth 4, exact) ----
    int b0 = lane << 2, b1 = (lane + 64) << 2, b2 = (lane + 128) << 2, b3 = (lane + 192) << 2;
    float mA, mB, mC, mD, mt0, mt1, m; int iA, iB, iC, iD, it0, it1, mi;
    {
        float p, q; int pi, qi;
        amax2(r0.x, b0+0, r0.y, b0+1, p, pi); amax2(r0.z, b0+2, r0.w, b0+3, q, qi);
        amax2(p, pi, q, qi, mA, iA);
        amax2(r1.x, b1+0, r1.y, b1+1, p, pi); amax2(r1.z, b1+2, r1.w, b1+3, q, qi);
        amax2(p, pi, q, qi, mB, iB);
        amax2(r2.x, b2+0, r2.y, b2+1, p, pi); amax2(r2.z, b2+2, r2.w, b2+3, q, qi);
        amax2(p, pi, q, qi, mC, iC);
        amax2(r3.x, b3+0, r3.y, b3+1, p, pi); amax2(r3.z, b3+2, r3.w, b3+3, q, qi);
        amax2(p, pi, q, qi, mD, iD);
    }
    amax2(mA, iA, mB, iB, mt0, it0);
    amax2(mC, iC, mD, iD, mt1, it1);
    amax2(mt0, it0, mt1, it1, m, mi);

    // ---- wave butterfly argmax (prefer smaller index on ties) ----
    #pragma unroll
    for (int off = 1; off < 64; off <<= 1) {
        float om = __shfl_xor(m, off, 64);
        int   oi = __shfl_xor(mi, off, 64);
        if (om > m || (om == m && oi < mi)) { m = om; mi = oi; }
    }

    // ---- exp sums (order identical to verified kernel) ----
    float se = 0.f, sx = 0.f;
#define ACCUM(v) { float t_ = (v) - m; float e_ = __expf(t_); se += e_; sx = fmaf(e_, t_, sx); }
    ACCUM(r0.x) ACCUM(r0.y) ACCUM(r0.z) ACCUM(r0.w)
    ACCUM(r1.x) ACCUM(r1.y) ACCUM(r1.z) ACCUM(r1.w)
    ACCUM(r2.x) ACCUM(r2.y) ACCUM(r2.z) ACCUM(r2.w)
    ACCUM(r3.x) ACCUM(r3.y) ACCUM(r3.z) ACCUM(r3.w)
#undef ACCUM
    #pragma unroll
    for (int off = 1; off < 64; off <<= 1) {
        se += __shfl_xor(se, off, 64);
        sx += __shfl_xor(sx, off, 64);
    }

    float Z    = se;
    float logZ = logf(Z);
    float conf = 1.0f / Z;
    float uncv = logZ - sx / Z;

    int f4 = label >> 2, slot = label & 3, it = f4 >> 6;
    float4 q = (it == 0) ? r0 : (it == 1) ? r1 : (it == 2) ? r2 : r3;
    float cand = (slot == 0) ? q.x : (slot == 1) ? q.y : (slot == 2) ? q.z : q.w;
    float xl = __shfl(cand, f4 & 63, 64);
    float lp = (xl - m) - logZ;

    if (lane == 0) {
        unc_o[row]   = uncv;
        confs_o[row] = (mi == label) ? conf : -conf;
    }
    mn = fminf(mn, uncv);
    mx = fmaxf(mx, uncv);
    ssum += lp;
}

#define LOADROW(P, q0, q1, q2, q3) \
    q0 = (P)[lane]; q1 = (P)[lane + 64]; q2 = (P)[lane + 128]; \
    q3 = make_float4(-1e30f, -1e30f, -1e30f, -1e30f); \
    if (lane < 58) q3 = (P)[lane + 192];

__global__ __launch_bounds__(256, 4) void k1_rowstats(
        const float* __restrict__ logits, const int* __restrict__ labels,
        float* __restrict__ unc_o, float* __restrict__ confs_o,
        float* __restrict__ blk_mn, float* __restrict__ blk_mx, float* __restrict__ blk_s)
{
    const int wave = threadIdx.x >> 6;
    const int lane = threadIdx.x & 63;
    const int row0 = (blockIdx.x * 4 + wave) * 4;   // 4 consecutive rows per wave
    const float4* p = (const float4*)(logits + (size_t)row0 * NC);   // row stride = 250 f4

    int lab0 = labels[row0], lab1 = labels[row0 + 1];
    int lab2 = labels[row0 + 2], lab3 = labels[row0 + 3];

    float mn = 1e30f, mx = -1e30f, ssum = 0.f;
    float4 a0, a1, a2, a3, b0, b1, b2, b3;

    // software pipeline: keep next row's loads in flight under current row's compute
    LOADROW(p,        a0, a1, a2, a3)
    LOADROW(p + 250,  b0, b1, b2, b3)
    row_process(a0, a1, a2, a3, lane, lab0, row0,     unc_o, confs_o, mn, mx, ssum);
    LOADROW(p + 500,  a0, a1, a2, a3)
    row_process(b0, b1, b2, b3, lane, lab1, row0 + 1, unc_o, confs_o, mn, mx, ssum);
    LOADROW(p + 750,  b0, b1, b2, b3)
    row_process(a0, a1, a2, a3, lane, lab2, row0 + 2, unc_o, confs_o, mn, mx, ssum);
    row_process(b0, b1, b2, b3, lane, lab3, row0 + 3, unc_o, confs_o, mn, mx, ssum);

    // per-block partials (NO contended atomics)
    __shared__ float s_mn[4], s_mx[4], s_s[4];
    if (lane == 0) { s_mn[wave] = mn; s_mx[wave] = mx; s_s[wave] = ssum; }
    __syncthreads();
    if (threadIdx.x == 0) {
        blk_mn[blockIdx.x] = fminf(fminf(s_mn[0], s_mn[1]), fminf(s_mn[2], s_mn[3]));
        blk_mx[blockIdx.x] = fmaxf(fmaxf(s_mx[0], s_mx[1]), fmaxf(s_mx[2], s_mx[3]));
        blk_s [blockIdx.x] = (s_s[0] + s_s[1]) + (s_s[2] + s_s[3]);
    }
}

__global__ __launch_bounds__(256) void k2_reduce(
        const float* __restrict__ blk_mn, const float* __restrict__ blk_mx,
        const float* __restrict__ blk_s,
        float* __restrict__ ce_sum, unsigned* __restrict__ umin_b,
        unsigned* __restrict__ umax_b, float* __restrict__ bins)
{
    // single block: deterministic final reduction + bins init
    float mn = 1e30f, mx = -1e30f, s = 0.f;
    for (int i = threadIdx.x; i < NBLK1; i += 256) {
        mn = fminf(mn, blk_mn[i]);
        mx = fmaxf(mx, blk_mx[i]);
        s += blk_s[i];
    }
    #pragma unroll
    for (int off = 1; off < 64; off <<= 1) {
        mn = fminf(mn, __shfl_xor(mn, off, 64));
        mx = fmaxf(mx, __shfl_xor(mx, off, 64));
        s += __shfl_xor(s, off, 64);
    }
    __shared__ float smn[4], smx[4], ss[4];
    int wave = threadIdx.x >> 6;
    if ((threadIdx.x & 63) == 0) { smn[wave] = mn; smx[wave] = mx; ss[wave] = s; }
    __syncthreads();
    if (threadIdx.x == 0) {
        mn = fminf(fminf(smn[0], smn[1]), fminf(smn[2], smn[3]));
        mx = fmaxf(fmaxf(smx[0], smx[1]), fmaxf(smx[2], smx[3]));
        s  = (ss[0] + ss[1]) + (ss[2] + ss[3]);
        *ce_sum = s;
        *umin_b = __float_as_uint(mn);
        *umax_b = __float_as_uint(mx);
    }
    if (threadIdx.x < 88) bins[threadIdx.x] = 0.f;
}

__global__ __launch_bounds__(256) void k3_hist(
        const float* __restrict__ unc, const float* __restrict__ confs,
        const unsigned* __restrict__ umin_b, const unsigned* __restrict__ umax_b,
        float* __restrict__ bins)
{
    __shared__ float h[88];
    for (int i = threadIdx.x; i < 88; i += 256) h[i] = 0.f;
    __syncthreads();
    float umin = __uint_as_float(*umin_b);
    float umax = __uint_as_float(*umax_b);
    float du = umax - umin;

    int i = blockIdx.x * 256 + threadIdx.x;
    float u  = unc[i];
    float cs = confs[i];
    float conf = fabsf(cs);
    bool  acc  = cs > 0.f;
    float tu = tanhf(u);

    // bucket = smallest t with u <= umin + (t*0.05)*du ; 21 => never certain
    int b = NTH;
    #pragma unroll
    for (int t = NTH - 1; t >= 0; --t) {
        float th = umin + ((float)t * 0.05f) * du;
        if (u <= th) b = t;
    }
    float w = acc ? conf : (1.f - conf);
    int base = acc ? 0 : 44;
    atomicAdd(&h[base + b],       w * (1.f - tu));  // -> n_ac / n_ic (certain side)
    atomicAdd(&h[base + 22 + b],  w * tu);          // -> n_au / n_iu (uncertain side)
    __syncthreads();
    for (int i2 = threadIdx.x; i2 < 88; i2 += 256) {
        float v = h[i2];
        if (v != 0.f) atomicAdd(&bins[i2], v);
    }
}

__global__ void k4_final(const float* __restrict__ bins, const float* __restrict__ ce_sum,
                         float* __restrict__ out)
{
    if (threadIdx.x != 0 || blockIdx.x != 0) return;
    float tot_au = 0.f, tot_iu = 0.f;
    for (int b = 0; b < 22; ++b) { tot_au += bins[22 + b]; tot_iu += bins[66 + b]; }
    float cac = 0.f, cau = 0.f, cic = 0.f, ciu = 0.f;
    float avu[NTH];
    for (int t = 0; t < NTH; ++t) {
        cac += bins[t]; cau += bins[22 + t]; cic += bins[44 + t]; ciu += bins[66 + t];
        float nac = cac, nau = tot_au - cau, nic = cic, niu = tot_iu - ciu;
        avu[t] = (nac + niu) / (nac + nau + nic + niu + 1e-12f);
    }
    float auc = 0.f;
    for (int t = 0; t + 1 < NTH; ++t) auc += 0.5f * (avu[t + 1] + avu[t]) * 0.05f;
    float avu_loss = -3.0f * logf(auc + 1e-12f);
    float ce = -(*ce_sum) / (float)NROWS;
    out[0] = avu_loss + ce;
}

extern "C" void kernel_launch(void* const* d_in, const int* in_sizes, int n_in,
                              void* d_out, int out_size, void* d_ws, size_t ws_size,
                              hipStream_t stream)
{
    const float* logits = (const float*)d_in[0];
    const int*   labels = (const int*)d_in[1];
    float* ws    = (float*)d_ws;
    float* unc   = ws;
    float* confs = ws + NROWS;
    float* bins  = ws + 2 * NROWS;                 // 88 floats
    float* ce_sum = ws + 2 * NROWS + 1024;
    unsigned* umin_b = (unsigned*)(ws + 2 * NROWS + 2048);
    unsigned* umax_b = (unsigned*)(ws + 2 * NROWS + 3072);
    float* blk_mn = ws + 2 * NROWS + 4096;
    float* blk_mx = blk_mn + NBLK1;
    float* blk_s  = blk_mx + NBLK1;

    hipLaunchKernelGGL(k1_rowstats, dim3(NBLK1), dim3(256), 0, stream,
                       logits, labels, unc, confs, blk_mn, blk_mx, blk_s);
    hipLaunchKernelGGL(k2_reduce, dim3(1), dim3(256), 0, stream,
                       blk_mn, blk_mx, blk_s, ce_sum, umin_b, umax_b, bins);
    hipLaunchKernelGGL(k3_hist, dim3(NROWS / 256), dim3(256), 0, stream,
                       unc, confs, umin_b, umax_b, bins);
    hipLaunchKernelGGL(k4_final, dim3(1), dim3(64), 0, stream,
                       bins, ce_sum, (float*)d_out);
}